// Round 1
// baseline (92.769 us; speedup 1.0000x reference)
//
#include <hip/hip_runtime.h>

#define INFV 3.0e38f

__device__ __forceinline__ float wave_reduce_sum(float v) {
#pragma unroll
    for (int m = 1; m < 64; m <<= 1) v += __shfl_xor(v, m);
    return v;
}

// Block-wide sum of v (256 threads) -> one atomicAdd into *dst.
__device__ __forceinline__ void block_sum_atomic(float v, float* dst, float* sbuf) {
    v = wave_reduce_sum(v);
    int lane = threadIdx.x & 63;
    int wid  = threadIdx.x >> 6;
    if (lane == 0) sbuf[wid] = v;
    __syncthreads();
    if (threadIdx.x == 0) atomicAdd(dst, sbuf[0] + sbuf[1] + sbuf[2] + sbuf[3]);
    __syncthreads();
}

// pc_mask is bool in the reference; harness may deliver it as u8 (1B) or i32 (4B).
// Probe bytes at offsets 4i+1 (safe for both layouts, < 16384B):
//   i32 layout: values are 0/1 -> those bytes are all 0.
//   u8  layout: those bytes are mask elements (~90% ones) -> some nonzero.
__device__ __forceinline__ bool mask_mode_u8(const void* mp) {
    const unsigned char* p = (const unsigned char*)mp;
    unsigned char v = p[(threadIdx.x & 63) * 4 + 1];
    return __ballot(v != 0) != 0ull;
}

__device__ __forceinline__ bool mask_at(const void* mp, int idx, bool u8) {
    if (u8) return ((const unsigned char*)mp)[idx] != 0;
    return ((const int*)mp)[idx] != 0;
}

// ws layout (floats):
// [0..15]  d1sum per batch (sum over valid i of sqrt(min_j d^2))
// [16..31] msum per batch
// [32] d2sum (sum over all b,j of sqrt(masked min_i d^2))
// [33] cdsum (sum over all b,k of sqrt(min_i d^2))
// [34] divsum (sum over all b, pairs of diversity terms)
// [35] posesum (fully normalized loss_pose)
// [36] nocssum
// [37] deltasum
// [38] distsum (sum over b of 512-dim norms)
__global__ __launch_bounds__(256) void loss_main(
    const float* __restrict__ pts,          // (16,1024,3)
    const float* __restrict__ recon_delta,  // (16,1024,3)
    const float* __restrict__ kpt,          // (16,96,3)
    const float* __restrict__ recon,        // (16,1024,3)
    const float* __restrict__ t_label,      // (16,3)
    const float* __restrict__ r_label,      // (16,3,3)
    const float* __restrict__ s_label,      // (16,3)
    const float* __restrict__ pred_r,       // (16,3,3)
    const float* __restrict__ pred_t,       // (16,3)
    const float* __restrict__ pred_s,       // (16,3)
    const float* __restrict__ kpt_nocs,     // (16,96,3)
    const void*  __restrict__ pc_mask,      // (16,1024) bool
    const float* __restrict__ d_pn,         // (16,512)
    const float* __restrict__ d_ul,         // (16,512)
    float* __restrict__ ws)
{
    __shared__ float sbuf[4];
    const int t = threadIdx.x;
    const int blk = blockIdx.x;

    if (blk < 256) {
        // ---- Role A: d1[i] = min_j ||pts_i - recon_j||, masked sums per batch
        int b = blk >> 4, sub = blk & 15;
        int il = t >> 2, q = t & 3;
        int i = sub * 64 + il;
        const float* P = pts + ((b << 10) + i) * 3;
        float px = P[0], py = P[1], pz = P[2];
        const float* Rp = recon + ((b << 10) + q * 256) * 3;
        float dmin = INFV;
#pragma unroll 4
        for (int j = 0; j < 256; ++j) {
            float dx = px - Rp[0], dy = py - Rp[1], dz = pz - Rp[2];
            Rp += 3;
            float d = dx * dx + dy * dy + dz * dz;
            dmin = fminf(dmin, d);
        }
        dmin = fminf(dmin, __shfl_xor(dmin, 1));
        dmin = fminf(dmin, __shfl_xor(dmin, 2));
        bool u8 = mask_mode_u8(pc_mask);
        float mv = mask_at(pc_mask, (b << 10) + i, u8) ? 1.0f : 0.0f;
        float c1 = (q == 0) ? sqrtf(dmin) * mv : 0.0f;
        float c2 = (q == 0) ? mv : 0.0f;
        block_sum_atomic(c1, ws + b, sbuf);
        block_sum_atomic(c2, ws + 16 + b, sbuf);

    } else if (blk < 512) {
        // ---- Role B: d2[j] = min over VALID i of ||pts_i - recon_j||
        int bb = blk - 256;
        int b = bb >> 4, sub = bb & 15;
        int j = sub * 64 + (t >> 2), q = t & 3;
        const float* Rp = recon + ((b << 10) + j) * 3;
        float rx = Rp[0], ry = Rp[1], rz = Rp[2];
        bool u8 = mask_mode_u8(pc_mask);
        const float* Pp = pts + ((b << 10) + q * 256) * 3;
        int mbase = (b << 10) + q * 256;
        float dmin = INFV;
#pragma unroll 4
        for (int i = 0; i < 256; ++i) {
            float dx = rx - Pp[0], dy = ry - Pp[1], dz = rz - Pp[2];
            Pp += 3;
            float d = dx * dx + dy * dy + dz * dz;
            bool mv = mask_at(pc_mask, mbase + i, u8);
            dmin = fminf(dmin, mv ? d : INFV);
        }
        dmin = fminf(dmin, __shfl_xor(dmin, 1));
        dmin = fminf(dmin, __shfl_xor(dmin, 2));
        float c = (q == 0) ? sqrtf(dmin) : 0.0f;
        block_sum_atomic(c, ws + 32, sbuf);

    } else if (blk < 536) {
        // ---- Role C: cd[k] = min_i ||pts_i - kpt_k||
        int g = (blk - 512) * 256 + t;            // 0..6143 = 16b * 96k * 4q
        int b = g / 384;
        int r2 = g - b * 384;
        int k = r2 >> 2, q = r2 & 3;
        const float* K = kpt + (b * 96 + k) * 3;
        float kx = K[0], ky = K[1], kz = K[2];
        const float* Pp = pts + ((b << 10) + q * 256) * 3;
        float dmin = INFV;
#pragma unroll 4
        for (int i = 0; i < 256; ++i) {
            float dx = kx - Pp[0], dy = ky - Pp[1], dz = kz - Pp[2];
            Pp += 3;
            dmin = fminf(dmin, dx * dx + dy * dy + dz * dz);
        }
        dmin = fminf(dmin, __shfl_xor(dmin, 1));
        dmin = fminf(dmin, __shfl_xor(dmin, 2));
        float c = (q == 0) ? sqrtf(dmin) : 0.0f;
        block_sum_atomic(c, ws + 33, sbuf);

    } else if (blk < 552) {
        // ---- Role D: diversity (per batch, 96x96 pairs)
        int b = blk - 536;
        const float* K = kpt + b * 288;
        float acc = 0.0f;
        for (int r = 0; r < 36; ++r) {
            int p = r * 256 + t;                  // 0..9215
            int ki = p / 96, kj = p - ki * 96;
            float dx = K[ki * 3 + 0] - K[kj * 3 + 0];
            float dy = K[ki * 3 + 1] - K[kj * 3 + 1];
            float dz = K[ki * 3 + 2] - K[kj * 3 + 2];
            float d = sqrtf(dx * dx + dy * dy + dz * dz + 1e-12f);
            if (ki != kj && d < 0.1f) acc += 1.0f - d * 10.0f;
        }
        block_sum_atomic(acc, ws + 34, sbuf);

    } else if (blk < 568) {
        // ---- Role E: recon_delta norms (16384 3-vectors)
        int e = blk - 552;
        float acc = 0.0f;
#pragma unroll
        for (int r = 0; r < 4; ++r) {
            int id = e * 1024 + r * 256 + t;
            const float* D = recon_delta + id * 3;
            acc += sqrtf(D[0] * D[0] + D[1] * D[1] + D[2] * D[2]);
        }
        block_sum_atomic(acc, ws + 37, sbuf);

    } else if (blk == 568) {
        // ---- Role F: pose (fully normalized)
        float c = 0.0f;
        if (t < 48) {                              // column norms of dR
            int b = t / 3, j = t - b * 3;
            float s = 0.0f;
#pragma unroll
            for (int i2 = 0; i2 < 3; ++i2) {
                float d = pred_r[b * 9 + i2 * 3 + j] - r_label[b * 9 + i2 * 3 + j];
                s += d * d;
            }
            c = sqrtf(s) * (1.0f / 48.0f);
        } else if (t >= 64 && t < 80) {            // translation norms
            int b = t - 64;
            float s = 0.0f;
#pragma unroll
            for (int d2i = 0; d2i < 3; ++d2i) {
                float d = pred_t[b * 3 + d2i] - t_label[b * 3 + d2i];
                s += d * d;
            }
            c = sqrtf(s) * (1.0f / 16.0f);
        } else if (t >= 96 && t < 112) {           // size norms
            int b = t - 96;
            float s = 0.0f;
#pragma unroll
            for (int d2i = 0; d2i < 3; ++d2i) {
                float d = pred_s[b * 3 + d2i] - s_label[b * 3 + d2i];
                s += d * d;
            }
            c = sqrtf(s) * (1.0f / 16.0f);
        }
        block_sum_atomic(c, ws + 35, sbuf);

    } else if (blk == 569) {
        // ---- Role G: NOCS smooth-L1 (16x96 keypoints)
        float acc = 0.0f;
#pragma unroll
        for (int r = 0; r < 6; ++r) {
            int item = r * 256 + t;               // 0..1535
            int b = item / 96, k = item - b * 96;
            float sx = s_label[b * 3], sy = s_label[b * 3 + 1], sz = s_label[b * 3 + 2];
            float sn = sqrtf(sx * sx + sy * sy + sz * sz) + 1e-8f;
            float v0 = (kpt[(b * 96 + k) * 3 + 0] - t_label[b * 3 + 0]) / sn;
            float v1 = (kpt[(b * 96 + k) * 3 + 1] - t_label[b * 3 + 1]) / sn;
            float v2 = (kpt[(b * 96 + k) * 3 + 2] - t_label[b * 3 + 2]) / sn;
#pragma unroll
            for (int e = 0; e < 3; ++e) {
                float gt = v0 * r_label[b * 9 + e] + v1 * r_label[b * 9 + 3 + e] +
                           v2 * r_label[b * 9 + 6 + e];
                float diff = fabsf(kpt_nocs[(b * 96 + k) * 3 + e] - gt);
                acc += (diff > 0.1f) ? (diff - 0.05f) : (diff * diff * 5.0f);
            }
        }
        block_sum_atomic(acc, ws + 36, sbuf);

    } else {
        // ---- Role H: distillation norms (16 batches x 512 dims)
        int b = t >> 4, off = t & 15;
        float s = 0.0f;
        for (int c2 = off; c2 < 512; c2 += 16) {
            float d = d_pn[b * 512 + c2] - d_ul[b * 512 + c2];
            s += d * d;
        }
        s += __shfl_xor(s, 1);
        s += __shfl_xor(s, 2);
        s += __shfl_xor(s, 4);
        s += __shfl_xor(s, 8);
        float c = (off == 0) ? sqrtf(s) : 0.0f;
        block_sum_atomic(c, ws + 38, sbuf);
    }
}

__global__ __launch_bounds__(64) void loss_finalize(const float* __restrict__ ws,
                                                    float* __restrict__ out) {
    int t = threadIdx.x;
    float v = 0.0f;
    if (t < 16) v = 0.5f * ws[t] / ws[16 + t];     // 0.5 * d1m per batch
#pragma unroll
    for (int m = 1; m < 16; m <<= 1) v += __shfl_xor(v, m);
    if (t == 0) {
        float recon = v * (1.0f / 16.0f) + 0.5f * ws[32] * (1.0f / 16384.0f);
        float pose  = ws[35];
        float nocs  = ws[36] * (1.0f / 1536.0f);
        float cd    = ws[33] * (1.0f / 1536.0f);
        float divl  = ws[34] * (1.0f / (9120.0f * 16.0f));   // /(96*95)/16
        float delta = ws[37] * (1.0f / 16384.0f);
        float dist  = ws[38] * (1.0f / 16.0f);
        float all = pose + nocs + cd + divl + recon + delta + dist;
        out[0] = all;  out[1] = pose; out[2] = nocs;  out[3] = cd;
        out[4] = divl; out[5] = recon; out[6] = delta; out[7] = dist;
    }
}

extern "C" void kernel_launch(void* const* d_in, const int* in_sizes, int n_in,
                              void* d_out, int out_size, void* d_ws, size_t ws_size,
                              hipStream_t stream) {
    float* ws = (float*)d_ws;
    hipMemsetAsync(d_ws, 0, 64 * sizeof(float), stream);
    loss_main<<<571, 256, 0, stream>>>(
        (const float*)d_in[0],  (const float*)d_in[1],  (const float*)d_in[2],
        (const float*)d_in[3],  (const float*)d_in[4],  (const float*)d_in[5],
        (const float*)d_in[6],  (const float*)d_in[7],  (const float*)d_in[8],
        (const float*)d_in[9],  (const float*)d_in[10], (const void*)d_in[11],
        (const float*)d_in[12], (const float*)d_in[13], ws);
    loss_finalize<<<1, 64, 0, stream>>>(ws, (float*)d_out);
}

// Round 2
// 36.007 us; speedup vs baseline: 2.5764x; 2.5764x over previous
//
#include <hip/hip_runtime.h>

#define INFV 3.0e38f

// ws layout (float indices)
#define D1MIN 0        // 16*1024 partial min d^2 (uint-bitpattern, atomicMin)
#define D2MIN 16384    // 16*1024
#define CDMIN 32768    // 16*96 -> padded region 1536
#define ACC   34304    // accumulators:
// ACC+0..15  d1sum per batch, ACC+16..31 msum per batch,
// ACC+32 d2sum, ACC+33 cdsum, ACC+34 div, ACC+35 pose, ACC+36 nocs,
// ACC+37 delta, ACC+38 dist

__device__ __forceinline__ float wave_reduce_sum(float v) {
#pragma unroll
    for (int m = 1; m < 64; m <<= 1) v += __shfl_xor(v, m);
    return v;
}

__device__ __forceinline__ void block_sum_atomic(float v, float* dst, float* sbuf) {
    v = wave_reduce_sum(v);
    int lane = threadIdx.x & 63;
    int wid  = threadIdx.x >> 6;
    if (lane == 0) sbuf[wid] = v;
    __syncthreads();
    if (threadIdx.x == 0) atomicAdd(dst, sbuf[0] + sbuf[1] + sbuf[2] + sbuf[3]);
    __syncthreads();
}

// pc_mask may arrive as u8 (1B) or i32 (4B). Probe bytes at 4i+1.
__device__ __forceinline__ bool mask_mode_u8(const void* mp) {
    const unsigned char* p = (const unsigned char*)mp;
    unsigned char v = p[(threadIdx.x & 63) * 4 + 1];
    return __ballot(v != 0) != 0ull;
}

__device__ __forceinline__ bool mask_at(const void* mp, int idx, bool u8) {
    if (u8) return ((const unsigned char*)mp)[idx] != 0;
    return ((const int*)mp)[idx] != 0;
}

__global__ __launch_bounds__(256) void loss_main(
    const float* __restrict__ pts,          // (16,1024,3)
    const float* __restrict__ recon_delta,  // (16,1024,3)
    const float* __restrict__ kpt,          // (16,96,3)
    const float* __restrict__ recon,        // (16,1024,3)
    const float* __restrict__ t_label,      // (16,3)
    const float* __restrict__ r_label,      // (16,3,3)
    const float* __restrict__ s_label,      // (16,3)
    const float* __restrict__ pred_r,       // (16,3,3)
    const float* __restrict__ pred_t,       // (16,3)
    const float* __restrict__ pred_s,       // (16,3)
    const float* __restrict__ kpt_nocs,     // (16,96,3)
    const void*  __restrict__ pc_mask,      // (16,1024) bool
    const float* __restrict__ d_pn,         // (16,512)
    const float* __restrict__ d_ul,         // (16,512)
    float* __restrict__ ws)
{
    __shared__ float lds[1536];
    __shared__ float sbuf[4];
    const int t = threadIdx.x;
    const int blk = blockIdx.x;

    if (blk < 128) {
        // ---- d1: block = (b, jc). Stage 128 recon pts; thread owns 4 pts i.
        int b = blk >> 3, jc = blk & 7;
        const float* src = recon + ((b << 10) + jc * 128) * 3;
        for (int e = t; e < 384; e += 256) lds[e] = src[e];
        __syncthreads();
        float px[4], py[4], pz[4], dmin[4];
#pragma unroll
        for (int p = 0; p < 4; ++p) {
            const float* P = pts + ((b << 10) + t + (p << 8)) * 3;
            px[p] = P[0]; py[p] = P[1]; pz[p] = P[2];
            dmin[p] = INFV;
        }
#pragma unroll 4
        for (int j = 0; j < 128; ++j) {
            float rx = lds[3 * j], ry = lds[3 * j + 1], rz = lds[3 * j + 2];
#pragma unroll
            for (int p = 0; p < 4; ++p) {
                float dx = px[p] - rx, dy = py[p] - ry, dz = pz[p] - rz;
                dmin[p] = fminf(dmin[p], dx * dx + dy * dy + dz * dz);
            }
        }
        unsigned* dst = (unsigned*)ws + D1MIN + (b << 10);
#pragma unroll
        for (int p = 0; p < 4; ++p)
            atomicMin(dst + t + (p << 8), __float_as_uint(dmin[p]));

    } else if (blk < 256) {
        // ---- d2: block = (b, ic). Stage 128 pts (masked -> 1e18); thread owns 4 recon j.
        int bb = blk - 128;
        int b = bb >> 3, ic = bb & 7;
        bool u8 = mask_mode_u8(pc_mask);
        if (t < 128) {
            int i = ic * 128 + t;
            const float* P = pts + ((b << 10) + i) * 3;
            bool m = mask_at(pc_mask, (b << 10) + i, u8);
            lds[3 * t]     = m ? P[0] : 1e18f;
            lds[3 * t + 1] = m ? P[1] : 1e18f;
            lds[3 * t + 2] = m ? P[2] : 1e18f;
        }
        __syncthreads();
        float rx[4], ry[4], rz[4], dmin[4];
#pragma unroll
        for (int p = 0; p < 4; ++p) {
            const float* R = recon + ((b << 10) + t + (p << 8)) * 3;
            rx[p] = R[0]; ry[p] = R[1]; rz[p] = R[2];
            dmin[p] = INFV;
        }
#pragma unroll 4
        for (int i = 0; i < 128; ++i) {
            float qx = lds[3 * i], qy = lds[3 * i + 1], qz = lds[3 * i + 2];
#pragma unroll
            for (int p = 0; p < 4; ++p) {
                float dx = rx[p] - qx, dy = ry[p] - qy, dz = rz[p] - qz;
                dmin[p] = fminf(dmin[p], dx * dx + dy * dy + dz * dz);
            }
        }
        unsigned* dst = (unsigned*)ws + D2MIN + (b << 10);
#pragma unroll
        for (int p = 0; p < 4; ++p)
            atomicMin(dst + t + (p << 8), __float_as_uint(dmin[p]));

    } else if (blk < 288) {
        // ---- cd: block = (b, ic of 512 pts). threads t<192: (k, q-half of tile).
        int bb = blk - 256;
        int b = bb >> 1, ic = bb & 1;
        const float* src = pts + ((b << 10) + ic * 512) * 3;
        for (int e = t; e < 1536; e += 256) lds[e] = src[e];
        __syncthreads();
        if (t < 192) {
            int q = t / 96, k = t - q * 96;
            const float* K = kpt + (b * 96 + k) * 3;
            float kx = K[0], ky = K[1], kz = K[2];
            float dmin = INFV;
            int base = q << 8;
#pragma unroll 4
            for (int i = 0; i < 256; ++i) {
                float dx = kx - lds[3 * (base + i)];
                float dy = ky - lds[3 * (base + i) + 1];
                float dz = kz - lds[3 * (base + i) + 2];
                dmin = fminf(dmin, dx * dx + dy * dy + dz * dz);
            }
            atomicMin((unsigned*)ws + CDMIN + b * 96 + k, __float_as_uint(dmin));
        }

    } else if (blk < 304) {
        // ---- diversity: per batch, stage 96 kpts in LDS
        int b = blk - 288;
        const float* K = kpt + b * 288;
        for (int e = t; e < 288; e += 256) lds[e] = K[e];
        __syncthreads();
        float acc = 0.0f;
        for (int r = 0; r < 36; ++r) {
            int p = r * 256 + t;
            int ki = p / 96, kj = p - ki * 96;
            float dx = lds[ki * 3 + 0] - lds[kj * 3 + 0];
            float dy = lds[ki * 3 + 1] - lds[kj * 3 + 1];
            float dz = lds[ki * 3 + 2] - lds[kj * 3 + 2];
            float d = sqrtf(dx * dx + dy * dy + dz * dz + 1e-12f);
            if (ki != kj && d < 0.1f) acc += 1.0f - d * 10.0f;
        }
        block_sum_atomic(acc, ws + ACC + 34, sbuf);

    } else if (blk < 320) {
        // ---- recon_delta norms
        int e = blk - 304;
        float acc = 0.0f;
#pragma unroll
        for (int r = 0; r < 4; ++r) {
            int id = e * 1024 + r * 256 + t;
            const float* D = recon_delta + id * 3;
            acc += sqrtf(D[0] * D[0] + D[1] * D[1] + D[2] * D[2]);
        }
        block_sum_atomic(acc, ws + ACC + 37, sbuf);

    } else if (blk == 320) {
        // ---- pose
        float c = 0.0f;
        if (t < 48) {
            int b = t / 3, j = t - b * 3;
            float s = 0.0f;
#pragma unroll
            for (int i2 = 0; i2 < 3; ++i2) {
                float d = pred_r[b * 9 + i2 * 3 + j] - r_label[b * 9 + i2 * 3 + j];
                s += d * d;
            }
            c = sqrtf(s) * (1.0f / 48.0f);
        } else if (t >= 64 && t < 80) {
            int b = t - 64;
            float s = 0.0f;
#pragma unroll
            for (int d2i = 0; d2i < 3; ++d2i) {
                float d = pred_t[b * 3 + d2i] - t_label[b * 3 + d2i];
                s += d * d;
            }
            c = sqrtf(s) * (1.0f / 16.0f);
        } else if (t >= 96 && t < 112) {
            int b = t - 96;
            float s = 0.0f;
#pragma unroll
            for (int d2i = 0; d2i < 3; ++d2i) {
                float d = pred_s[b * 3 + d2i] - s_label[b * 3 + d2i];
                s += d * d;
            }
            c = sqrtf(s) * (1.0f / 16.0f);
        }
        block_sum_atomic(c, ws + ACC + 35, sbuf);

    } else if (blk == 321) {
        // ---- NOCS smooth-L1
        float acc = 0.0f;
#pragma unroll
        for (int r = 0; r < 6; ++r) {
            int item = r * 256 + t;
            int b = item / 96, k = item - b * 96;
            float sx = s_label[b * 3], sy = s_label[b * 3 + 1], sz = s_label[b * 3 + 2];
            float sn = sqrtf(sx * sx + sy * sy + sz * sz) + 1e-8f;
            float v0 = (kpt[(b * 96 + k) * 3 + 0] - t_label[b * 3 + 0]) / sn;
            float v1 = (kpt[(b * 96 + k) * 3 + 1] - t_label[b * 3 + 1]) / sn;
            float v2 = (kpt[(b * 96 + k) * 3 + 2] - t_label[b * 3 + 2]) / sn;
#pragma unroll
            for (int e = 0; e < 3; ++e) {
                float gt = v0 * r_label[b * 9 + e] + v1 * r_label[b * 9 + 3 + e] +
                           v2 * r_label[b * 9 + 6 + e];
                float diff = fabsf(kpt_nocs[(b * 96 + k) * 3 + e] - gt);
                acc += (diff > 0.1f) ? (diff - 0.05f) : (diff * diff * 5.0f);
            }
        }
        block_sum_atomic(acc, ws + ACC + 36, sbuf);

    } else {
        // ---- distillation
        int b = t >> 4, off = t & 15;
        float s = 0.0f;
        for (int c2 = off; c2 < 512; c2 += 16) {
            float d = d_pn[b * 512 + c2] - d_ul[b * 512 + c2];
            s += d * d;
        }
        s += __shfl_xor(s, 1);
        s += __shfl_xor(s, 2);
        s += __shfl_xor(s, 4);
        s += __shfl_xor(s, 8);
        float c = (off == 0) ? sqrtf(s) : 0.0f;
        block_sum_atomic(c, ws + ACC + 38, sbuf);
    }
}

__global__ __launch_bounds__(256) void loss_reduce(float* __restrict__ ws,
                                                   const void* __restrict__ pc_mask) {
    __shared__ float sbuf[4];
    const int t = threadIdx.x;
    const int blk = blockIdx.x;
    if (blk < 16) {
        bool u8 = mask_mode_u8(pc_mask);
        float s1 = 0.0f, s2 = 0.0f;
#pragma unroll
        for (int r = 0; r < 4; ++r) {
            int i = (r << 8) + t;
            float v = sqrtf(ws[D1MIN + (blk << 10) + i]);
            float m = mask_at(pc_mask, (blk << 10) + i, u8) ? 1.0f : 0.0f;
            s1 += v * m;
            s2 += m;
        }
        block_sum_atomic(s1, ws + ACC + blk, sbuf);
        block_sum_atomic(s2, ws + ACC + 16 + blk, sbuf);
    } else if (blk < 32) {
        int b = blk - 16;
        float s = 0.0f;
#pragma unroll
        for (int r = 0; r < 4; ++r)
            s += sqrtf(ws[D2MIN + (b << 10) + (r << 8) + t]);
        block_sum_atomic(s, ws + ACC + 32, sbuf);
    } else {
        float s = 0.0f;
#pragma unroll
        for (int r = 0; r < 6; ++r)
            s += sqrtf(ws[CDMIN + r * 256 + t]);
        block_sum_atomic(s, ws + ACC + 33, sbuf);
    }
}

__global__ __launch_bounds__(64) void loss_finalize(const float* __restrict__ ws,
                                                    float* __restrict__ out) {
    int t = threadIdx.x;
    float v = 0.0f;
    if (t < 16) v = 0.5f * ws[ACC + t] / ws[ACC + 16 + t];
#pragma unroll
    for (int m = 1; m < 16; m <<= 1) v += __shfl_xor(v, m);
    if (t == 0) {
        float recon = v * (1.0f / 16.0f) + 0.5f * ws[ACC + 32] * (1.0f / 16384.0f);
        float pose  = ws[ACC + 35];
        float nocs  = ws[ACC + 36] * (1.0f / 1536.0f);
        float cd    = ws[ACC + 33] * (1.0f / 1536.0f);
        float divl  = ws[ACC + 34] * (1.0f / (9120.0f * 16.0f));
        float delta = ws[ACC + 37] * (1.0f / 16384.0f);
        float dist  = ws[ACC + 38] * (1.0f / 16.0f);
        float all = pose + nocs + cd + divl + recon + delta + dist;
        out[0] = all;  out[1] = pose;  out[2] = nocs;  out[3] = cd;
        out[4] = divl; out[5] = recon; out[6] = delta; out[7] = dist;
    }
}

extern "C" void kernel_launch(void* const* d_in, const int* in_sizes, int n_in,
                              void* d_out, int out_size, void* d_ws, size_t ws_size,
                              hipStream_t stream) {
    float* ws = (float*)d_ws;
    // min arrays -> 0x7f7f7f7f (huge positive float / max-ish uint for atomicMin)
    hipMemsetAsync(d_ws, 0x7F, (size_t)ACC * 4, stream);
    // accumulators -> 0
    hipMemsetAsync((char*)d_ws + (size_t)ACC * 4, 0, 64 * 4, stream);
    loss_main<<<323, 256, 0, stream>>>(
        (const float*)d_in[0],  (const float*)d_in[1],  (const float*)d_in[2],
        (const float*)d_in[3],  (const float*)d_in[4],  (const float*)d_in[5],
        (const float*)d_in[6],  (const float*)d_in[7],  (const float*)d_in[8],
        (const float*)d_in[9],  (const float*)d_in[10], (const void*)d_in[11],
        (const float*)d_in[12], (const float*)d_in[13], ws);
    loss_reduce<<<33, 256, 0, stream>>>(ws, (const void*)d_in[11]);
    loss_finalize<<<1, 64, 0, stream>>>(ws, (float*)d_out);
}